// Round 3
// baseline (723.535 us; speedup 1.0000x reference)
//
#include <hip/hip_runtime.h>
#include <hip/hip_bf16.h>

// FMLayer: out[b, p] = <w[j1], w[j2]> * x[b, j1] * x[b, j2] for triu pairs (j1<j2)
// N=512, K=4, B=1024, P=130816.
// Inputs fp32, output fp32 (established by round-1/2 forensics).
// Pure store-BW bound: 536 MB fp32 output -> ~85 us floor at 6.3 TB/s.

#define NF      512
#define KDIM    4
#define BATCH   1024
#define NPAIRS  130816   // 512*511/2
#define BT      16       // batch rows per block
#define TPB     256

__global__ __launch_bounds__(TPB) void fm_kernel(
    const float* __restrict__ x,      // [BATCH, NF] fp32
    const float* __restrict__ w,      // [NF, KDIM] fp32
    float* __restrict__ out)          // [BATCH, NPAIRS] fp32
{
    const int j1  = blockIdx.x;                         // 0 .. NF-2
    const int b0  = blockIdx.y * BT;
    const int L   = (NF - 1) - j1;                      // pairs in this row
    const int off = j1 * (NF - 1) - (j1 * (j1 - 1)) / 2;

    // weight row j1 (wave-uniform -> scalar loads)
    const float wa0 = w[j1 * KDIM + 0];
    const float wa1 = w[j1 * KDIM + 1];
    const float wa2 = w[j1 * KDIM + 2];
    const float wa3 = w[j1 * KDIM + 3];

    __shared__ float wd[NF - 1];   // wdot for this row, reused across BT batch rows

    for (int t = threadIdx.x; t < L; t += TPB) {
        const int j2 = j1 + 1 + t;
        const float d = wa0 * w[j2 * KDIM + 0]
                      + wa1 * w[j2 * KDIM + 1]
                      + wa2 * w[j2 * KDIM + 2]
                      + wa3 * w[j2 * KDIM + 3];
        wd[t] = d;
    }
    __syncthreads();

    for (int bi = 0; bi < BT; ++bi) {
        const int b = b0 + bi;
        const float xj1 = x[(size_t)b * NF + j1];
        const float* __restrict__ xrow = x + (size_t)b * NF + (j1 + 1);
        float* __restrict__ orow = out + (size_t)b * NPAIRS + off;
        for (int t = threadIdx.x; t < L; t += TPB) {
            orow[t] = wd[t] * xj1 * xrow[t];
        }
    }
}

extern "C" void kernel_launch(void* const* d_in, const int* in_sizes, int n_in,
                              void* d_out, int out_size, void* d_ws, size_t ws_size,
                              hipStream_t stream) {
    const float* x = (const float*)d_in[0];     // [1024, 512] fp32
    const float* w = (const float*)d_in[1];     // [512, 4]   fp32
    float* out = (float*)d_out;                 // [1024, 130816] fp32

    dim3 grid(NF - 1, BATCH / BT);   // 511 x 64 = 32704 blocks
    fm_kernel<<<grid, TPB, 0, stream>>>(x, w, out);
}